// Round 1
// baseline (513.411 us; speedup 1.0000x reference)
//
#include <hip/hip_runtime.h>
#include <stdint.h>

// CoLA encoder layer, fully fused on MI355X (gfx950).
// Key identity: Q only feeds S = Q@C_K/sqrt(D)  =>  S = x@M + s0 with
//   M = W_Q^T @ C_K / 32,  s0 = b_Q @ C_K / 32.  The layer is then row-local.
// Pipeline per 64-token block: x->bf16 LDS -> S-GEMM -> softmax*mask ->
// attn-GEMM -> +x -> LN1 -> conv-GEMM -> +bc,leaky,+h -> LN2 -> out.

#define NTHREADS 512

typedef float  f32x4  __attribute__((ext_vector_type(4)));
typedef short  s16x8  __attribute__((ext_vector_type(8)));
typedef __bf16 bf16x8 __attribute__((ext_vector_type(8)));

__device__ __forceinline__ uint16_t f2bf(float f) {
  uint32_t b = __builtin_bit_cast(uint32_t, f);
  b += 0x7FFFu + ((b >> 16) & 1u);          // RNE
  return (uint16_t)(b >> 16);
}
__device__ __forceinline__ float bf2f(uint16_t u) {
  return __builtin_bit_cast(float, ((uint32_t)u) << 16);
}
__device__ __forceinline__ f32x4 MFMA(s16x8 a, s16x8 b, f32x4 c) {
  return __builtin_amdgcn_mfma_f32_16x16x32_bf16(
      __builtin_bit_cast(bf16x8, a), __builtin_bit_cast(bf16x8, b), c, 0, 0, 0);
}

// ---------------- K0a: M^T[a][d] = (1/32) * sum_e W_Q[e][d]*C_K[e][a] ----------------
__global__ void k0_m(const float* __restrict__ WQ, const float* __restrict__ CK,
                     uint16_t* __restrict__ MbfT) {
  __shared__ float wq[32][16];
  __shared__ float ck[32][64];
  const int t  = threadIdx.x;
  const int d0 = blockIdx.x * 16;
  const int a  = t >> 2, dq = t & 3;
  float acc[4] = {0.f, 0.f, 0.f, 0.f};
  for (int e0 = 0; e0 < 1024; e0 += 32) {
    {
      int i0 = t * 2, r = i0 >> 4, c = i0 & 15;
      float2 v = *(const float2*)(WQ + (size_t)(e0 + r) * 1024 + d0 + c);
      wq[r][c] = v.x; wq[r][c + 1] = v.y;
    }
#pragma unroll
    for (int j = 0; j < 8; j++) {
      int idx = t + j * 256, r = idx >> 6, c = idx & 63;
      ck[r][c] = CK[(size_t)(e0 + r) * 64 + c];
    }
    __syncthreads();
    for (int r = 0; r < 32; r++) {
      float cv = ck[r][a];
#pragma unroll
      for (int i = 0; i < 4; i++) acc[i] += cv * wq[r][dq * 4 + i];
    }
    __syncthreads();
  }
#pragma unroll
  for (int i = 0; i < 4; i++) {
    int d = d0 + dq * 4 + i;
    MbfT[(size_t)a * 1024 + d] = f2bf(acc[i] * 0.03125f);
  }
}

// ---------------- K0b: s0[a] = (1/32) * sum_e b_Q[e]*C_K[e][a] ----------------
__global__ void k0_s0(const float* __restrict__ bQ, const float* __restrict__ CK,
                      float* __restrict__ s0) {
  __shared__ float part[4][64];
  const int t = threadIdx.x, a = t & 63, q = t >> 6;
  float s = 0.f;
  for (int e = q * 256; e < (q + 1) * 256; e++) s += bQ[e] * CK[(size_t)e * 64 + a];
  part[q][a] = s;
  __syncthreads();
  if (q == 0) s0[a] = (part[0][a] + part[1][a] + part[2][a] + part[3][a]) * 0.03125f;
}

// ---------------- K0c: bf16 conversion of C_V (layout kept [d][a]) and Wc ([e][d]) ----------------
__global__ void k0_cvt(const float* __restrict__ CV, const float* __restrict__ Wc,
                       uint16_t* __restrict__ CVbf, uint16_t* __restrict__ Wcbf) {
  int i4 = blockIdx.x * 256 + threadIdx.x;
  const float4* src;
  uint16_t* dst;
  if (i4 < 16384) { src = (const float4*)CV; dst = CVbf; }
  else            { src = (const float4*)Wc; dst = Wcbf; i4 -= 16384; }
  float4 v = src[i4];
  uint32_t lo = (uint32_t)f2bf(v.x) | ((uint32_t)f2bf(v.y) << 16);
  uint32_t hi = (uint32_t)f2bf(v.z) | ((uint32_t)f2bf(v.w) << 16);
  uint2 pk; pk.x = lo; pk.y = hi;
  *(uint2*)(dst + (size_t)i4 * 4) = pk;
}

// ---------------- Main fused kernel ----------------
// grid 512, block 512 (8 waves), 64 tokens/block, dynamic LDS 155648 B:
//   xs  [64][1024] bf16, XOR-swizzled (byte ^= (row&7)<<4)   offset 0,      131072 B
//   Asm [64][64]   bf16, swizzled                            offset 131072,   8192 B
//   Ssm [64][64]   f32                                       offset 139264,  16384 B
//   stats (LN2 mean/rinv) reuses Asm region.
__global__ __launch_bounds__(NTHREADS, 2) void fused_main(
    const float* __restrict__ x, const int* __restrict__ mask,
    const float* __restrict__ s0, const uint16_t* __restrict__ MbfT,
    const uint16_t* __restrict__ CVbf, const uint16_t* __restrict__ Wcbf,
    const float* __restrict__ g1, const float* __restrict__ be1,
    const float* __restrict__ bc, const float* __restrict__ g2,
    const float* __restrict__ be2, float* __restrict__ out) {
  extern __shared__ char smem[];
  char*  xs    = smem;
  char*  asmb  = smem + 131072;
  float* Ssm   = (float*)(smem + 139264);
  float* stats = (float*)(smem + 131072);

  const int tid = threadIdx.x;
  const int w = tid >> 6, l = tid & 63;
  const int ln = l & 15, kg = l >> 4;
  const size_t tok0 = (size_t)blockIdx.x * 64;

  // ---- 1. load x tile -> bf16, swizzled LDS
  {
    const float* xg = x + tok0 * 1024;
#pragma unroll
    for (int i = 0; i < 16; i++) {
      int g = tid + i * NTHREADS;          // 16B-granule id, 0..8191
      int row = g >> 7, c8 = g & 127;
      const float4* p = (const float4*)(xg + (size_t)row * 1024 + c8 * 8);
      float vb[8];
      *(float4*)(vb) = p[0]; *(float4*)(vb + 4) = p[1];
      s16x8 pk;
#pragma unroll
      for (int e = 0; e < 8; e++) pk[e] = (short)f2bf(vb[e]);
      uint32_t ad = (uint32_t)(row * 2048 + c8 * 16) ^ ((uint32_t)(row & 7) << 4);
      *(s16x8*)(xs + ad) = pk;
    }
  }
  __syncthreads();

  // ---- 2. S = x @ M   (64x64, K=1024); wave w: rtile=w>>1, ctiles {(w&1)*2, (w&1)*2+1}
  {
    const int rt = w >> 1;
    const int c0 = ((w & 1) * 2) * 16 + ln;
    const int c1 = ((w & 1) * 2 + 1) * 16 + ln;
    f32x4 sa0 = {0.f, 0.f, 0.f, 0.f}, sa1 = {0.f, 0.f, 0.f, 0.f};
    for (int ks = 0; ks < 32; ks++) {
      int row = rt * 16 + ln;
      uint32_t ad = (uint32_t)(row * 2048 + ks * 64 + kg * 16) ^ ((uint32_t)(row & 7) << 4);
      s16x8 af = *(const s16x8*)(xs + ad);
      s16x8 b0 = *(const s16x8*)(MbfT + (size_t)c0 * 1024 + ks * 32 + kg * 8);
      s16x8 b1 = *(const s16x8*)(MbfT + (size_t)c1 * 1024 + ks * 32 + kg * 8);
      sa0 = MFMA(af, b0, sa0);
      sa1 = MFMA(af, b1, sa1);
    }
#pragma unroll
    for (int r = 0; r < 4; r++) {
      int row = rt * 16 + kg * 4 + r;
      Ssm[row * 64 + c0] = sa0[r] + s0[c0];
      Ssm[row * 64 + c1] = sa1[r] + s0[c1];
    }
  }
  __syncthreads();

  // ---- 3. row softmax (8 threads/row) * mask -> Asm bf16 swizzled
  {
    int row = tid >> 3, g8 = tid & 7;
    float v[8];
#pragma unroll
    for (int i = 0; i < 8; i++) v[i] = Ssm[row * 64 + g8 * 8 + i];
    float m = v[0];
#pragma unroll
    for (int i = 1; i < 8; i++) m = fmaxf(m, v[i]);
    m = fmaxf(m, __shfl_xor(m, 1));
    m = fmaxf(m, __shfl_xor(m, 2));
    m = fmaxf(m, __shfl_xor(m, 4));
    float s = 0.f;
#pragma unroll
    for (int i = 0; i < 8; i++) { v[i] = __expf(v[i] - m); s += v[i]; }
    s += __shfl_xor(s, 1); s += __shfl_xor(s, 2); s += __shfl_xor(s, 4);
    float inv = (float)mask[tok0 + row] / s;
    s16x8 pk;
#pragma unroll
    for (int i = 0; i < 8; i++) pk[i] = (short)f2bf(v[i] * inv);
    uint32_t ad = (uint32_t)(row * 128 + g8 * 16) ^ ((uint32_t)(row & 7) << 4);
    *(s16x8*)(asmb + ad) = pk;
  }
  __syncthreads();

  // ---- 4. attn = A @ C_V^T (64x1024, K=64); wave w owns cols [w*128, w*128+128)
  {
    f32x4 acc[4][8];
#pragma unroll
    for (int a_ = 0; a_ < 4; a_++)
#pragma unroll
      for (int b_ = 0; b_ < 8; b_++) acc[a_][b_] = f32x4{0.f, 0.f, 0.f, 0.f};
#pragma unroll
    for (int ks = 0; ks < 2; ks++) {
      s16x8 af[4];
#pragma unroll
      for (int rt = 0; rt < 4; rt++) {
        int row = rt * 16 + ln;
        uint32_t ad = (uint32_t)(row * 128 + ks * 64 + kg * 16) ^ ((uint32_t)(row & 7) << 4);
        af[rt] = *(const s16x8*)(asmb + ad);
      }
#pragma unroll
      for (int cc = 0; cc < 8; cc++) {
        int dcol = (w * 8 + cc) * 16 + ln;
        s16x8 bf = *(const s16x8*)(CVbf + (size_t)dcol * 64 + ks * 32 + kg * 8);
#pragma unroll
        for (int rt = 0; rt < 4; rt++) acc[rt][cc] = MFMA(af[rt], bf, acc[rt][cc]);
      }
    }
    // epilogue: xs = bf16( x + attn )   (each element owned by exactly one lane)
#pragma unroll
    for (int cc = 0; cc < 8; cc++) {
      int col = (w * 8 + cc) * 16 + ln;
#pragma unroll
      for (int rt = 0; rt < 4; rt++)
#pragma unroll
        for (int r = 0; r < 4; r++) {
          int row = rt * 16 + kg * 4 + r;
          uint32_t ad = (uint32_t)(row * 2048 + col * 2) ^ ((uint32_t)(row & 7) << 4);
          float xv = bf2f(*(const uint16_t*)(xs + ad));
          *(uint16_t*)(xs + ad) = f2bf(xv + acc[rt][cc][r]);
        }
    }
  }
  __syncthreads();

  // ---- 5. LN1 in place on xs (8 threads/row, shfl reductions)
  {
    int row = tid >> 3, g8 = tid & 7;
    float sum = 0.f, sq = 0.f;
#pragma unroll
    for (int i = 0; i < 16; i++) {
      uint32_t ad = (uint32_t)(row * 2048 + (g8 * 16 + i) * 16) ^ ((uint32_t)(row & 7) << 4);
      s16x8 vv = *(const s16x8*)(xs + ad);
#pragma unroll
      for (int e = 0; e < 8; e++) { float f = bf2f((uint16_t)vv[e]); sum += f; sq += f * f; }
    }
    sum += __shfl_xor(sum, 1); sum += __shfl_xor(sum, 2); sum += __shfl_xor(sum, 4);
    sq  += __shfl_xor(sq, 1);  sq  += __shfl_xor(sq, 2);  sq  += __shfl_xor(sq, 4);
    float mean = sum * (1.0f / 1024.0f);
    float var  = fmaxf((sq - 1024.0f * mean * mean) * (1.0f / 1023.0f), 0.f);
    float rinv = 1.0f / (sqrtf(var) + 1e-6f);
#pragma unroll
    for (int i = 0; i < 16; i++) {
      uint32_t ad = (uint32_t)(row * 2048 + (g8 * 16 + i) * 16) ^ ((uint32_t)(row & 7) << 4);
      s16x8 vv = *(const s16x8*)(xs + ad);
      int col0 = g8 * 128 + i * 8;
      s16x8 hv;
#pragma unroll
      for (int e = 0; e < 8; e++) {
        float f = bf2f((uint16_t)vv[e]);
        hv[e] = (short)f2bf(g1[col0 + e] * (f - mean) * rinv + be1[col0 + e]);
      }
      *(s16x8*)(xs + ad) = hv;
    }
  }
  __syncthreads();

  // ---- 6. conv = h @ Wc^T (64x1024, K=1024), then r = h + leaky(conv + bc) in place
  {
    f32x4 acc[4][8];
#pragma unroll
    for (int a_ = 0; a_ < 4; a_++)
#pragma unroll
      for (int b_ = 0; b_ < 8; b_++) acc[a_][b_] = f32x4{0.f, 0.f, 0.f, 0.f};
    for (int ks = 0; ks < 32; ks++) {
      s16x8 af[4];
#pragma unroll
      for (int rt = 0; rt < 4; rt++) {
        int row = rt * 16 + ln;
        uint32_t ad = (uint32_t)(row * 2048 + ks * 64 + kg * 16) ^ ((uint32_t)(row & 7) << 4);
        af[rt] = *(const s16x8*)(xs + ad);
      }
#pragma unroll
      for (int cc = 0; cc < 8; cc++) {
        int ecol = (w * 8 + cc) * 16 + ln;
        s16x8 bf = *(const s16x8*)(Wcbf + (size_t)ecol * 1024 + ks * 32 + kg * 8);
#pragma unroll
        for (int rt = 0; rt < 4; rt++) acc[rt][cc] = MFMA(af[rt], bf, acc[rt][cc]);
      }
    }
    __syncthreads();  // all waves done reading h before we overwrite with r
#pragma unroll
    for (int cc = 0; cc < 8; cc++) {
      int col = (w * 8 + cc) * 16 + ln;
      float bcv = bc[col];
#pragma unroll
      for (int rt = 0; rt < 4; rt++)
#pragma unroll
        for (int r = 0; r < 4; r++) {
          int row = rt * 16 + kg * 4 + r;
          float conv = acc[rt][cc][r] + bcv;
          float act  = conv > 0.f ? conv : 0.01f * conv;
          uint32_t ad = (uint32_t)(row * 2048 + col * 2) ^ ((uint32_t)(row & 7) << 4);
          float h = bf2f(*(const uint16_t*)(xs + ad));
          *(uint16_t*)(xs + ad) = f2bf(h + act);
        }
    }
  }
  __syncthreads();

  // ---- 7. LN2 stats (8 threads/row) -> stats LDS
  {
    int row = tid >> 3, g8 = tid & 7;
    float sum = 0.f, sq = 0.f;
#pragma unroll
    for (int i = 0; i < 16; i++) {
      uint32_t ad = (uint32_t)(row * 2048 + (g8 * 16 + i) * 16) ^ ((uint32_t)(row & 7) << 4);
      s16x8 vv = *(const s16x8*)(xs + ad);
#pragma unroll
      for (int e = 0; e < 8; e++) { float f = bf2f((uint16_t)vv[e]); sum += f; sq += f * f; }
    }
    sum += __shfl_xor(sum, 1); sum += __shfl_xor(sum, 2); sum += __shfl_xor(sum, 4);
    sq  += __shfl_xor(sq, 1);  sq  += __shfl_xor(sq, 2);  sq  += __shfl_xor(sq, 4);
    float mean = sum * (1.0f / 1024.0f);
    float var  = fmaxf((sq - 1024.0f * mean * mean) * (1.0f / 1023.0f), 0.f);
    float rinv = 1.0f / (sqrtf(var) + 1e-6f);
    if (g8 == 0) { stats[row * 2] = mean; stats[row * 2 + 1] = rinv; }
  }
  __syncthreads();

  // ---- 8. normalize + coalesced fp32 store
  {
#pragma unroll
    for (int i = 0; i < 16; i++) {
      int g = tid + i * NTHREADS;
      int row = g >> 7, c8 = g & 127;
      uint32_t ad = (uint32_t)(row * 2048 + c8 * 16) ^ ((uint32_t)(row & 7) << 4);
      s16x8 vv = *(const s16x8*)(xs + ad);
      float mean = stats[row * 2], rinv = stats[row * 2 + 1];
      int col0 = c8 * 8;
      float ov[8];
#pragma unroll
      for (int e = 0; e < 8; e++) {
        float f = bf2f((uint16_t)vv[e]);
        ov[e] = g2[col0 + e] * (f - mean) * rinv + be2[col0 + e];
      }
      float* op = out + (tok0 + row) * 1024 + col0;
      *(float4*)op = *(float4*)(ov);
      *(float4*)(op + 4) = *(float4*)(ov + 4);
    }
  }
}

extern "C" void kernel_launch(void* const* d_in, const int* in_sizes, int n_in,
                              void* d_out, int out_size, void* d_ws, size_t ws_size,
                              hipStream_t stream) {
  const float* x   = (const float*)d_in[0];
  const int*   msk = (const int*)d_in[1];
  const float* WQ  = (const float*)d_in[2];
  const float* bQ  = (const float*)d_in[3];
  const float* CK  = (const float*)d_in[4];
  const float* CV  = (const float*)d_in[5];
  const float* g1  = (const float*)d_in[6];
  const float* be1 = (const float*)d_in[7];
  const float* Wc  = (const float*)d_in[8];
  const float* bc  = (const float*)d_in[9];
  const float* g2  = (const float*)d_in[10];
  const float* be2 = (const float*)d_in[11];
  float* out = (float*)d_out;

  char* ws = (char*)d_ws;
  uint16_t* Wcbf = (uint16_t*)ws;                // 2 MiB
  uint16_t* MbfT = (uint16_t*)(ws + 2097152);    // 128 KiB
  uint16_t* CVbf = (uint16_t*)(ws + 2228224);    // 128 KiB
  float*    s0   = (float*)(ws + 2359296);       // 256 B

  (void)hipFuncSetAttribute((const void*)fused_main,
                            hipFuncAttributeMaxDynamicSharedMemorySize, 155648);

  k0_m  <<<64,   256, 0, stream>>>(WQ, CK, MbfT);
  k0_s0 <<<1,    256, 0, stream>>>(bQ, CK, s0);
  k0_cvt<<<1088, 256, 0, stream>>>(CV, Wc, CVbf, Wcbf);
  fused_main<<<512, NTHREADS, 155648, stream>>>(x, msk, s0, MbfT, CVbf, Wcbf,
                                                g1, be1, bc, g2, be2, out);
}

// Round 2
// 489.455 us; speedup vs baseline: 1.0489x; 1.0489x over previous
//
#include <hip/hip_runtime.h>
#include <stdint.h>

// CoLA encoder layer, fused, v2.
// Identities used:
//   S = x@M + s0,  M = W_Q^T C_K/32  (Q-GEMM folded away)
//   LN1 folded into conv GEMM: conv = rinv*(h' @ (g1*Wc)^T) - rinv*mean*u + vb
//     u[e] = sum_d g1[d]Wc[e][d],  vb[e] = sum_d be1[d]Wc[e][d] + bc[e]
// All main GEMMs computed TRANSPOSED (C'[feat][tok]) so the MFMA C-fragment
// holds 4 contiguous features per lane -> vector (b64) epilogues, LN stats
// and final store directly from registers.

#define NT 1024   // 16 waves

typedef float  f32x4  __attribute__((ext_vector_type(4)));
typedef short  s16x8  __attribute__((ext_vector_type(8)));
typedef short  s16x4  __attribute__((ext_vector_type(4)));
typedef __bf16 bf16x8 __attribute__((ext_vector_type(8)));

__device__ __forceinline__ uint16_t f2bf(float f) {
  uint32_t b = __builtin_bit_cast(uint32_t, f);
  b += 0x7FFFu + ((b >> 16) & 1u);
  return (uint16_t)(b >> 16);
}
__device__ __forceinline__ float bf2f(uint16_t u) {
  return __builtin_bit_cast(float, ((uint32_t)u) << 16);
}
__device__ __forceinline__ f32x4 MFMA(s16x8 a, s16x8 b, f32x4 c) {
  return __builtin_amdgcn_mfma_f32_16x16x32_bf16(
      __builtin_bit_cast(bf16x8, a), __builtin_bit_cast(bf16x8, b), c, 0, 0, 0);
}

// ---------------- merged preprocessing (one launch) ----------------
// blocks [0,64): MbfT ; [64,1152): cvt CV->CVbf, g1*Wc->Wpbf ; 1152: s0 ;
// [1153,1409): u[e], vb[e]
__global__ void k0_all(const float* __restrict__ WQ, const float* __restrict__ bQ,
                       const float* __restrict__ CK, const float* __restrict__ CV,
                       const float* __restrict__ Wc, const float* __restrict__ g1,
                       const float* __restrict__ be1, const float* __restrict__ bc,
                       uint16_t* __restrict__ MbfT, float* __restrict__ s0,
                       uint16_t* __restrict__ CVbf, uint16_t* __restrict__ Wpbf,
                       float* __restrict__ u, float* __restrict__ vb) {
  __shared__ float sm[2560];
  const int b = blockIdx.x, t = threadIdx.x;
  if (b < 64) {
    // MbfT[a][d] = (1/32) sum_e WQ[e][d]*CK[e][a]
    float (*wq)[16] = (float(*)[16])sm;
    float (*ck)[64] = (float(*)[64])(sm + 512);
    const int d0 = b * 16, a = t >> 2, dq = t & 3;
    float acc[4] = {0.f, 0.f, 0.f, 0.f};
    for (int e0 = 0; e0 < 1024; e0 += 32) {
      {
        int i0 = t * 2, r = i0 >> 4, c = i0 & 15;
        float2 v = *(const float2*)(WQ + (size_t)(e0 + r) * 1024 + d0 + c);
        wq[r][c] = v.x; wq[r][c + 1] = v.y;
      }
#pragma unroll
      for (int j = 0; j < 8; j++) {
        int idx = t + j * 256, r = idx >> 6, c = idx & 63;
        ck[r][c] = CK[(size_t)(e0 + r) * 64 + c];
      }
      __syncthreads();
      for (int r = 0; r < 32; r++) {
        float cv = ck[r][a];
#pragma unroll
        for (int i = 0; i < 4; i++) acc[i] += cv * wq[r][dq * 4 + i];
      }
      __syncthreads();
    }
#pragma unroll
    for (int i = 0; i < 4; i++)
      MbfT[(size_t)a * 1024 + d0 + dq * 4 + i] = f2bf(acc[i] * 0.03125f);
  } else if (b < 1152) {
    int i4 = (b - 64) * 256 + t;
    if (i4 < 16384) {
      float4 v = ((const float4*)CV)[i4];
      uint2 pk;
      pk.x = (uint32_t)f2bf(v.x) | ((uint32_t)f2bf(v.y) << 16);
      pk.y = (uint32_t)f2bf(v.z) | ((uint32_t)f2bf(v.w) << 16);
      *(uint2*)(CVbf + (size_t)i4 * 4) = pk;
    } else {
      int f4 = i4 - 16384;
      int d = (f4 * 4) & 1023;
      float4 v = ((const float4*)Wc)[f4];
      float4 g = *(const float4*)(g1 + d);
      v.x *= g.x; v.y *= g.y; v.z *= g.z; v.w *= g.w;
      uint2 pk;
      pk.x = (uint32_t)f2bf(v.x) | ((uint32_t)f2bf(v.y) << 16);
      pk.y = (uint32_t)f2bf(v.z) | ((uint32_t)f2bf(v.w) << 16);
      *(uint2*)(Wpbf + (size_t)f4 * 4) = pk;
    }
  } else if (b == 1152) {
    // s0[a] = (1/32) sum_e bQ[e]*CK[e][a]
    float (*part)[64] = (float(*)[64])sm;
    const int a = t & 63, q = t >> 6;
    float s = 0.f;
    for (int e = q * 256; e < (q + 1) * 256; e++) s += bQ[e] * CK[(size_t)e * 64 + a];
    part[q][a] = s;
    __syncthreads();
    if (q == 0) s0[a] = (part[0][a] + part[1][a] + part[2][a] + part[3][a]) * 0.03125f;
  } else {
    // u[e] = sum_d g1[d]Wc[e][d] ; vb[e] = sum_d be1[d]Wc[e][d] + bc[e]
    const int e = (b - 1153) * 4 + (t >> 6), l = t & 63;
    float su = 0.f, sv = 0.f;
#pragma unroll
    for (int j = 0; j < 16; j++) {
      int d = l + 64 * j;
      float w = Wc[(size_t)e * 1024 + d];
      su += g1[d] * w;
      sv += be1[d] * w;
    }
#pragma unroll
    for (int m = 1; m <= 32; m <<= 1) { su += __shfl_xor(su, m); sv += __shfl_xor(sv, m); }
    if (l == 0) { u[e] = su; vb[e] = sv + bc[e]; }
  }
}

// ---------------- main fused kernel ----------------
// grid 512, block 1024 (16 waves), 64 tokens/block, dyn LDS 147968 B:
//   xs    [64 tok][1024] bf16, XOR-swizzle byte^=(tok&7)<<4    @0       131072
//   asmb  [64 tok][64 a] bf16, same swizzle                    @131072    8192
//   part  float2[16 w][64 tok]                                 @139264    8192
//   stats float [64 tok][2] (mean,rinv) - reused LN1/LN2       @147456     512
__global__ __launch_bounds__(NT, 4) void fused_main(
    const float* __restrict__ x, const int* __restrict__ mask,
    const float* __restrict__ s0, const uint16_t* __restrict__ MbfT,
    const uint16_t* __restrict__ CVbf, const uint16_t* __restrict__ Wpbf,
    const float* __restrict__ u, const float* __restrict__ vb,
    const float* __restrict__ g1, const float* __restrict__ be1,
    const float* __restrict__ g2, const float* __restrict__ be2,
    float* __restrict__ out) {
  extern __shared__ char smem[];
  char*   xs    = smem;
  char*   asmb  = smem + 131072;
  float2* part  = (float2*)(smem + 139264);   // [16][64]
  float*  stats = (float*)(smem + 147456);    // [64][2]

  const int tid = threadIdx.x;
  const int w = tid >> 6, l = tid & 63;
  const int ln = l & 15, kg = l >> 4;
  const size_t tok0 = (size_t)blockIdx.x * 64;
  const int E0 = w * 64;   // this wave's 64-feature slice (4 tiles of 16)

  // ---- P1: x -> bf16 swizzled LDS
  {
    const float* xg = x + tok0 * 1024;
#pragma unroll
    for (int i = 0; i < 8; i++) {
      int g = tid + i * NT;              // 16B granule 0..8191
      int row = g >> 7, c8 = g & 127;
      const float4* p = (const float4*)(xg + (size_t)row * 1024 + c8 * 8);
      float vbuf[8];
      *(float4*)(vbuf) = p[0]; *(float4*)(vbuf + 4) = p[1];
      s16x8 pk;
#pragma unroll
      for (int e = 0; e < 8; e++) pk[e] = (short)f2bf(vbuf[e]);
      uint32_t ad = (uint32_t)(row * 2048 + c8 * 16) ^ ((uint32_t)(row & 7) << 4);
      *(s16x8*)(xs + ad) = pk;
    }
  }
  __syncthreads();

  // ---- P2 (waves 0-3): S'[a][tok] = M @ x^T (+s0), softmax over a, -> asmb
  if (w < 4) {
    const int tokr = w * 16 + ln;
    f32x4 accs[4];
#pragma unroll
    for (int at = 0; at < 4; at++) accs[at] = f32x4{0.f, 0.f, 0.f, 0.f};
    for (int ks = 0; ks < 32; ks++) {
      uint32_t ad = (uint32_t)(tokr * 2048 + ks * 64 + kg * 16) ^ ((uint32_t)(tokr & 7) << 4);
      s16x8 bfr = *(const s16x8*)(xs + ad);
#pragma unroll
      for (int at = 0; at < 4; at++) {
        s16x8 af = *(const s16x8*)(MbfT + (size_t)(at * 16 + ln) * 1024 + ks * 32 + kg * 8);
        accs[at] = MFMA(af, bfr, accs[at]);
      }
    }
    float v[4][4], mx = -1e30f;
#pragma unroll
    for (int at = 0; at < 4; at++) {
      float4 s4 = *(const float4*)(s0 + at * 16 + kg * 4);
      const float* sp = (const float*)&s4;
#pragma unroll
      for (int r = 0; r < 4; r++) { v[at][r] = accs[at][r] + sp[r]; mx = fmaxf(mx, v[at][r]); }
    }
    mx = fmaxf(mx, __shfl_xor(mx, 16));
    mx = fmaxf(mx, __shfl_xor(mx, 32));
    float s = 0.f;
#pragma unroll
    for (int at = 0; at < 4; at++)
#pragma unroll
      for (int r = 0; r < 4; r++) { v[at][r] = __expf(v[at][r] - mx); s += v[at][r]; }
    s += __shfl_xor(s, 16);
    s += __shfl_xor(s, 32);
    float inv = (float)mask[tok0 + tokr] / s;
#pragma unroll
    for (int at = 0; at < 4; at++) {
      s16x4 pk;
#pragma unroll
      for (int r = 0; r < 4; r++) pk[r] = (short)f2bf(v[at][r] * inv);
      uint32_t ad = (uint32_t)(tokr * 128 + at * 32 + kg * 8) ^ ((uint32_t)(tokr & 7) << 4);
      *(s16x4*)(asmb + ad) = pk;
    }
  }
  __syncthreads();

  // ---- P4: attn'[d][tok] = C_V @ A^T (K=64); wave owns d in [E0,E0+64)
  float st[4], sq[4];
  {
    f32x4 acc[4][4];
#pragma unroll
    for (int et = 0; et < 4; et++)
#pragma unroll
      for (int tt = 0; tt < 4; tt++) acc[et][tt] = f32x4{0.f, 0.f, 0.f, 0.f};
#pragma unroll
    for (int ks = 0; ks < 2; ks++) {
      s16x8 bfr[4];
#pragma unroll
      for (int tt = 0; tt < 4; tt++) {
        int tokr = tt * 16 + ln;
        uint32_t ad = (uint32_t)(tokr * 128 + ks * 64 + kg * 16) ^ ((uint32_t)(tokr & 7) << 4);
        bfr[tt] = *(const s16x8*)(asmb + ad);
      }
#pragma unroll
      for (int et = 0; et < 4; et++) {
        s16x8 af = *(const s16x8*)(CVbf + (size_t)(E0 + et * 16 + ln) * 64 + ks * 32 + kg * 8);
#pragma unroll
        for (int tt = 0; tt < 4; tt++) acc[et][tt] = MFMA(af, bfr[tt], acc[et][tt]);
      }
    }
    // E4: h' = x + attn (b64 RMW in xs), LN1 partial stats from registers
#pragma unroll
    for (int tt = 0; tt < 4; tt++) { st[tt] = 0.f; sq[tt] = 0.f; }
#pragma unroll
    for (int et = 0; et < 4; et++)
#pragma unroll
      for (int tt = 0; tt < 4; tt++) {
        int tokr = tt * 16 + ln;
        int d = E0 + et * 16 + kg * 4;
        uint32_t ad = (uint32_t)(tokr * 2048 + d * 2) ^ ((uint32_t)(tokr & 7) << 4);
        s16x4 xv = *(const s16x4*)(xs + ad);
        s16x4 hv;
#pragma unroll
        for (int r = 0; r < 4; r++) {
          float h = bf2f((uint16_t)xv[r]) + acc[et][tt][r];
          st[tt] += h; sq[tt] += h * h;
          hv[r] = (short)f2bf(h);
        }
        *(s16x4*)(xs + ad) = hv;
      }
#pragma unroll
    for (int tt = 0; tt < 4; tt++) {
      st[tt] += __shfl_xor(st[tt], 16); st[tt] += __shfl_xor(st[tt], 32);
      sq[tt] += __shfl_xor(sq[tt], 16); sq[tt] += __shfl_xor(sq[tt], 32);
    }
    if (kg == 0) {
#pragma unroll
      for (int tt = 0; tt < 4; tt++) part[w * 64 + tt * 16 + ln] = float2{st[tt], sq[tt]};
    }
  }
  __syncthreads();
  if (tid < 64) {
    float s = 0.f, q = 0.f;
#pragma unroll
    for (int ww = 0; ww < 16; ww++) { float2 p = part[ww * 64 + tid]; s += p.x; q += p.y; }
    float mean = s * (1.0f / 1024.0f);
    float var  = fmaxf((q - 1024.0f * mean * mean) * (1.0f / 1023.0f), 0.f);
    stats[tid * 2] = mean;
    stats[tid * 2 + 1] = 1.0f / (sqrtf(var) + 1e-6f);
  }
  __syncthreads();

  // ---- P6: conv'[e][tok] = (g1*Wc) @ h'^T (K=1024), LN1 applied via u/vb
  {
    f32x4 acc[4][4];
#pragma unroll
    for (int et = 0; et < 4; et++)
#pragma unroll
      for (int tt = 0; tt < 4; tt++) acc[et][tt] = f32x4{0.f, 0.f, 0.f, 0.f};
    for (int ks = 0; ks < 32; ks++) {
      s16x8 bfr[4];
#pragma unroll
      for (int tt = 0; tt < 4; tt++) {
        int tokr = tt * 16 + ln;
        uint32_t ad = (uint32_t)(tokr * 2048 + ks * 64 + kg * 16) ^ ((uint32_t)(tokr & 7) << 4);
        bfr[tt] = *(const s16x8*)(xs + ad);
      }
#pragma unroll
      for (int et = 0; et < 4; et++) {
        s16x8 af = *(const s16x8*)(Wpbf + (size_t)(E0 + et * 16 + ln) * 1024 + ks * 32 + kg * 8);
#pragma unroll
        for (int tt = 0; tt < 4; tt++) acc[et][tt] = MFMA(af, bfr[tt], acc[et][tt]);
      }
    }
    // E6: conv = rinv*acc - rinv*mean*u + vb ; act = leaky ; h = LN1(h') ;
    //     r = h + act kept in acc regs ; LN2 partial stats
#pragma unroll
    for (int tt = 0; tt < 4; tt++) { st[tt] = 0.f; sq[tt] = 0.f; }
#pragma unroll
    for (int et = 0; et < 4; et++) {
      int e0 = E0 + et * 16 + kg * 4;
      float4 u4 = *(const float4*)(u + e0);
      float4 v4 = *(const float4*)(vb + e0);
      float4 gg = *(const float4*)(g1 + e0);
      float4 bb = *(const float4*)(be1 + e0);
      const float *uf = (const float*)&u4, *vf = (const float*)&v4;
      const float *gf = (const float*)&gg, *bf = (const float*)&bb;
#pragma unroll
      for (int tt = 0; tt < 4; tt++) {
        int tokr = tt * 16 + ln;
        float mean = stats[tokr * 2], rinv = stats[tokr * 2 + 1];
        uint32_t ad = (uint32_t)(tokr * 2048 + e0 * 2) ^ ((uint32_t)(tokr & 7) << 4);
        s16x4 hv = *(const s16x4*)(xs + ad);
#pragma unroll
        for (int r = 0; r < 4; r++) {
          float conv = acc[et][tt][r] * rinv - rinv * mean * uf[r] + vf[r];
          float act  = conv > 0.f ? conv : 0.01f * conv;
          float h    = gf[r] * (bf2f((uint16_t)hv[r]) - mean) * rinv + bf[r];
          float rr   = h + act;
          acc[et][tt][r] = rr;
          st[tt] += rr; sq[tt] += rr * rr;
        }
      }
    }
#pragma unroll
    for (int tt = 0; tt < 4; tt++) {
      st[tt] += __shfl_xor(st[tt], 16); st[tt] += __shfl_xor(st[tt], 32);
      sq[tt] += __shfl_xor(sq[tt], 16); sq[tt] += __shfl_xor(sq[tt], 32);
    }
    if (kg == 0) {
#pragma unroll
      for (int tt = 0; tt < 4; tt++) part[w * 64 + tt * 16 + ln] = float2{st[tt], sq[tt]};
    }
    __syncthreads();
    if (tid < 64) {
      float s = 0.f, q = 0.f;
#pragma unroll
      for (int ww = 0; ww < 16; ww++) { float2 p = part[ww * 64 + tid]; s += p.x; q += p.y; }
      float mean = s * (1.0f / 1024.0f);
      float var  = fmaxf((q - 1024.0f * mean * mean) * (1.0f / 1023.0f), 0.f);
      stats[tid * 2] = mean;
      stats[tid * 2 + 1] = 1.0f / (sqrtf(var) + 1e-6f);
    }
    __syncthreads();

    // ---- P8: LN2 from registers, coalesced float4 store
#pragma unroll
    for (int et = 0; et < 4; et++) {
      int e0 = E0 + et * 16 + kg * 4;
      float4 gg = *(const float4*)(g2 + e0);
      float4 bb = *(const float4*)(be2 + e0);
      const float *gf = (const float*)&gg, *bf = (const float*)&bb;
#pragma unroll
      for (int tt = 0; tt < 4; tt++) {
        int tokr = tt * 16 + ln;
        float mean = stats[tokr * 2], rinv = stats[tokr * 2 + 1];
        float4 o;
        o.x = gf[0] * (acc[et][tt][0] - mean) * rinv + bf[0];
        o.y = gf[1] * (acc[et][tt][1] - mean) * rinv + bf[1];
        o.z = gf[2] * (acc[et][tt][2] - mean) * rinv + bf[2];
        o.w = gf[3] * (acc[et][tt][3] - mean) * rinv + bf[3];
        *(float4*)(out + (tok0 + tokr) * 1024 + e0) = o;
      }
    }
  }
}

extern "C" void kernel_launch(void* const* d_in, const int* in_sizes, int n_in,
                              void* d_out, int out_size, void* d_ws, size_t ws_size,
                              hipStream_t stream) {
  const float* x   = (const float*)d_in[0];
  const int*   msk = (const int*)d_in[1];
  const float* WQ  = (const float*)d_in[2];
  const float* bQ  = (const float*)d_in[3];
  const float* CK  = (const float*)d_in[4];
  const float* CV  = (const float*)d_in[5];
  const float* g1  = (const float*)d_in[6];
  const float* be1 = (const float*)d_in[7];
  const float* Wc  = (const float*)d_in[8];
  const float* bc  = (const float*)d_in[9];
  const float* g2  = (const float*)d_in[10];
  const float* be2 = (const float*)d_in[11];
  float* out = (float*)d_out;

  char* ws = (char*)d_ws;
  uint16_t* Wpbf = (uint16_t*)ws;                 // 2 MiB
  uint16_t* MbfT = (uint16_t*)(ws + 2097152);     // 128 KiB
  uint16_t* CVbf = (uint16_t*)(ws + 2228224);     // 128 KiB
  float*    s0   = (float*)(ws + 2359296);        // 256 B
  float*    u    = (float*)(ws + 2359552);        // 4 KiB
  float*    vb   = (float*)(ws + 2363648);        // 4 KiB

  (void)hipFuncSetAttribute((const void*)fused_main,
                            hipFuncAttributeMaxDynamicSharedMemorySize, 147968);

  k0_all<<<1409, 256, 0, stream>>>(WQ, bQ, CK, CV, Wc, g1, be1, bc,
                                   MbfT, s0, CVbf, Wpbf, u, vb);
  fused_main<<<512, NT, 147968, stream>>>(x, msk, s0, MbfT, CVbf, Wpbf,
                                          u, vb, g1, be1, g2, be2, out);
}